// Round 1
// baseline (1477.632 us; speedup 1.0000x reference)
//
#include <hip/hip_runtime.h>
#include <hip/hip_bf16.h>

#define DI 2048
#define DM 1024
#define LSEQ 1024
#define NBATCH 2
#define NCH 16      // number of scan chunks
#define CHUNK 64    // steps per chunk
#define SUBC 16     // steps per LDS sub-tile

typedef float f4 __attribute__((ext_vector_type(4)));
typedef short s8v __attribute__((ext_vector_type(8)));
typedef unsigned short u4v __attribute__((ext_vector_type(4)));

__device__ __forceinline__ unsigned short f2bf(float f){
  union { float f; unsigned int u; } v; v.f = f;
  unsigned int u = v.u;
  unsigned int r = u + 0x7fffu + ((u >> 16) & 1u);
  return (unsigned short)(r >> 16);
}

__device__ __forceinline__ float softplus_f(float x){
  return (x > 20.f) ? x : log1pf(__expf(x));
}

// ---------------------------------------------------------------------------
// Generic GEMM: C[M,N] = A[M,K] * B[N,K]^T   (both row-major, fp32 in, fp32 out)
// bf16 MFMA 16x16x32, 128x128 tile, BK=32, 256 threads = 4 waves (2x2 of 64x64).
// M must be multiple of 128 and K multiple of 32 (true for all call sites).
// N is guarded (zero-fill staging, guarded C writes).
// ---------------------------------------------------------------------------
__global__ __launch_bounds__(256) void gemm_bt(
    const float* __restrict__ A, int lda,
    const float* __restrict__ B, int ldb,
    float* __restrict__ C, int ldc,
    int N, int K)
{
  constexpr int BK = 32;
  constexpr int LS = 40;            // padded LDS stride in shorts (80B) -> <=2-way conflicts
  __shared__ __align__(16) unsigned short As[128 * LS];
  __shared__ __align__(16) unsigned short Bs[128 * LS];

  const int tid  = threadIdx.x;
  const int lane = tid & 63;
  const int wid  = tid >> 6;
  const int wr   = (wid >> 1) * 64;   // wave row offset in tile
  const int wc   = (wid & 1) * 64;    // wave col offset in tile
  const int m0   = blockIdx.y * 128;
  const int n0   = blockIdx.x * 128;

  const f4 fz = {0.f, 0.f, 0.f, 0.f};
  f4 acc[4][4];
  #pragma unroll
  for (int i = 0; i < 4; ++i)
    #pragma unroll
    for (int j = 0; j < 4; ++j) acc[i][j] = fz;

  f4 ar[4], br[4];

  auto stage_load = [&](int k0){
    #pragma unroll
    for (int i = 0; i < 4; ++i){
      int g = tid + i * 256;
      int r = g >> 3, kk = (g & 7) << 2;
      ar[i] = *(const f4*)(A + (size_t)(m0 + r) * lda + k0 + kk);
      int n = n0 + r;
      br[i] = (n < N) ? *(const f4*)(B + (size_t)n * ldb + k0 + kk) : fz;
    }
  };
  auto stage_write = [&](){
    #pragma unroll
    for (int i = 0; i < 4; ++i){
      int g = tid + i * 256;
      int r = g >> 3, kk = (g & 7) << 2;
      u4v av, bv;
      #pragma unroll
      for (int j = 0; j < 4; ++j){ av[j] = f2bf(ar[i][j]); bv[j] = f2bf(br[i][j]); }
      *(u4v*)(&As[r * LS + kk]) = av;
      *(u4v*)(&Bs[r * LS + kk]) = bv;
    }
  };

  const int nk = K / BK;
  stage_load(0);
  for (int kt = 0; kt < nk; ++kt){
    __syncthreads();            // previous compute done with LDS
    stage_write();
    __syncthreads();
    if (kt + 1 < nk) stage_load((kt + 1) * BK);  // overlap next loads with MFMA

    s8v af[4], bfv[4];
    #pragma unroll
    for (int t = 0; t < 4; ++t){
      af[t]  = *(const s8v*)(&As[(wr + t * 16 + (lane & 15)) * LS + ((lane >> 4) << 3)]);
      bfv[t] = *(const s8v*)(&Bs[(wc + t * 16 + (lane & 15)) * LS + ((lane >> 4) << 3)]);
    }
    #pragma unroll
    for (int mt = 0; mt < 4; ++mt)
      #pragma unroll
      for (int nt = 0; nt < 4; ++nt)
        acc[mt][nt] = __builtin_amdgcn_mfma_f32_16x16x32_bf16(af[mt], bfv[nt], acc[mt][nt], 0, 0, 0);
  }

  // C/D layout (verified m89/m91): col = lane&15, row = (lane>>4)*4 + reg
  #pragma unroll
  for (int mt = 0; mt < 4; ++mt){
    int row = m0 + wr + mt * 16 + ((lane >> 4) << 2);
    #pragma unroll
    for (int nt = 0; nt < 4; ++nt){
      int col = n0 + wc + nt * 16 + (lane & 15);
      if (col < N){
        #pragma unroll
        for (int r = 0; r < 4; ++r)
          C[(size_t)(row + r) * ldc + col] = acc[mt][nt][r];
      }
    }
  }
}

// ---------------------------------------------------------------------------
// Causal depthwise conv1d (k=4) + SiLU.  xz: [B, L, 2*DI] (xs = cols 0..DI)
// xc: [B, L, DI]
// ---------------------------------------------------------------------------
__global__ __launch_bounds__(256) void conv_silu(
    const float* __restrict__ xz, const float* __restrict__ cw,
    const float* __restrict__ cb, float* __restrict__ xc)
{
  int t = blockIdx.x * 256 + threadIdx.x;   // over B*L*DI
  int d = t & (DI - 1);
  int l = (t >> 11) & (LSEQ - 1);
  int b = t >> 21;
  f4 w = *(const f4*)(cw + d * 4);
  float acc = cb[d];
  #pragma unroll
  for (int k = 0; k < 4; ++k){
    int ls = l - 3 + k;
    if (ls >= 0) acc += xz[((size_t)(b * LSEQ + ls)) * (2 * DI) + d] * w[k];
  }
  xc[t] = acc / (1.f + __expf(-acc));
}

// ---------------------------------------------------------------------------
// Selective scan, chunked-parallel (3 passes).
// delta_raw: [B,L,DI] pre-bias pre-softplus; u: [B,L,DI]; dbl: [B,L,96]
// hend/Ssum/Hinit: [B, NCH, DI, 16]
// ---------------------------------------------------------------------------
__global__ __launch_bounds__(256) void scan_passA(
    const float* __restrict__ delta_raw, const float* __restrict__ u_,
    const float* __restrict__ dbl, const float* __restrict__ dtb_,
    const float* __restrict__ A_log,
    float* __restrict__ hend, float* __restrict__ Ssum)
{
  const int tid = threadIdx.x;
  const int d   = blockIdx.x * 256 + tid;
  const int c   = blockIdx.y;
  const int b   = blockIdx.z;
  __shared__ float s_del[SUBC][256];
  __shared__ float s_u[SUBC][256];
  __shared__ float s_bc[SUBC][32];

  float Ar[16];
  #pragma unroll
  for (int n = 0; n < 16; ++n) Ar[n] = -__expf(A_log[(size_t)d * 16 + n]);
  const float dtb = dtb_[d];
  float h[16], S[16];
  #pragma unroll
  for (int n = 0; n < 16; ++n){ h[n] = 0.f; S[n] = 0.f; }

  for (int sc = 0; sc < CHUNK / SUBC; ++sc){
    const int l0 = c * CHUNK + sc * SUBC;
    __syncthreads();
    #pragma unroll
    for (int s = 0; s < SUBC; ++s){
      size_t idx = ((size_t)(b * LSEQ + l0 + s)) * DI + d;
      s_del[s][tid] = delta_raw[idx];
      s_u[s][tid]   = u_[idx];
    }
    for (int e = tid; e < SUBC * 32; e += 256){
      int s = e >> 5, j = e & 31;
      s_bc[s][j] = dbl[((size_t)(b * LSEQ + l0 + s)) * 96 + 64 + j];
    }
    __syncthreads();
    #pragma unroll
    for (int s = 0; s < SUBC; ++s){
      float delta = softplus_f(s_del[s][tid] + dtb);
      float du = delta * s_u[s][tid];
      #pragma unroll
      for (int n = 0; n < 16; ++n){
        float x = delta * Ar[n];
        S[n] += x;
        h[n] = h[n] * __expf(x) + du * s_bc[s][n];
      }
    }
  }
  size_t base = (((size_t)b * NCH + c) * DI + d) * 16;
  #pragma unroll
  for (int n = 0; n < 16; ++n){ hend[base + n] = h[n]; Ssum[base + n] = S[n]; }
}

// Inter-chunk recurrence. In-place: Hinit may alias hend (read-before-write per idx).
__global__ __launch_bounds__(256) void scan_passB(
    const float* __restrict__ hend, const float* __restrict__ Ssum,
    float* __restrict__ Hinit)
{
  int t = blockIdx.x * 256 + threadIdx.x;   // over B*DI*16
  int n = t & 15;
  int d = (t >> 4) & (DI - 1);
  int b = t >> 15;
  float carry = 0.f;
  for (int c = 0; c < NCH; ++c){
    size_t idx = (((size_t)b * NCH + c) * DI + d) * 16 + n;
    float he = hend[idx];
    float s  = Ssum[idx];
    Hinit[idx] = carry;
    carry = he + __expf(s) * carry;
  }
}

// Final pass: full local scan from Hinit, y = C.h + u*D, out = y * silu(z).
// yout may alias delta_raw (each block reads its tile into LDS before writing).
__global__ __launch_bounds__(256) void scan_passC(
    const float* __restrict__ delta_raw, const float* __restrict__ u_,
    const float* __restrict__ dbl, const float* __restrict__ xz,
    const float* __restrict__ dtb_, const float* __restrict__ A_log,
    const float* __restrict__ Dskip_, const float* __restrict__ Hinit,
    float* __restrict__ yout)
{
  const int tid = threadIdx.x;
  const int d   = blockIdx.x * 256 + tid;
  const int c   = blockIdx.y;
  const int b   = blockIdx.z;
  __shared__ float s_del[SUBC][256];
  __shared__ float s_u[SUBC][256];
  __shared__ float s_z[SUBC][256];
  __shared__ float s_bc[SUBC][32];

  float Ar[16];
  #pragma unroll
  for (int n = 0; n < 16; ++n) Ar[n] = -__expf(A_log[(size_t)d * 16 + n]);
  const float dtb = dtb_[d];
  const float Dk  = Dskip_[d];
  float h[16];
  size_t hbase = (((size_t)b * NCH + c) * DI + d) * 16;
  #pragma unroll
  for (int n = 0; n < 16; ++n) h[n] = Hinit[hbase + n];

  for (int sc = 0; sc < CHUNK / SUBC; ++sc){
    const int l0 = c * CHUNK + sc * SUBC;
    __syncthreads();
    #pragma unroll
    for (int s = 0; s < SUBC; ++s){
      size_t idx = ((size_t)(b * LSEQ + l0 + s)) * DI + d;
      s_del[s][tid] = delta_raw[idx];
      s_u[s][tid]   = u_[idx];
      s_z[s][tid]   = xz[((size_t)(b * LSEQ + l0 + s)) * (2 * DI) + DI + d];
    }
    for (int e = tid; e < SUBC * 32; e += 256){
      int s = e >> 5, j = e & 31;
      s_bc[s][j] = dbl[((size_t)(b * LSEQ + l0 + s)) * 96 + 64 + j];
    }
    __syncthreads();
    #pragma unroll
    for (int s = 0; s < SUBC; ++s){
      float delta = softplus_f(s_del[s][tid] + dtb);
      float du = delta * s_u[s][tid];
      float y = 0.f;
      #pragma unroll
      for (int n = 0; n < 16; ++n){
        float x = delta * Ar[n];
        h[n] = h[n] * __expf(x) + du * s_bc[s][n];
        y += h[n] * s_bc[s][16 + n];
      }
      y += s_u[s][tid] * Dk;
      float z = s_z[s][tid];
      yout[((size_t)(b * LSEQ + l0 + s)) * DI + d] = y * (z / (1.f + __expf(-z)));
    }
  }
}

// ---------------------------------------------------------------------------
// residual add + LayerNorm over D=1024. One block per row (b*l).
// Safe when y aliases out (per-thread read-before-write, block owns row).
// ---------------------------------------------------------------------------
__global__ __launch_bounds__(256) void resid_ln(
    const float* __restrict__ y, const float* __restrict__ resid,
    const float* __restrict__ w, const float* __restrict__ b,
    float* __restrict__ out)
{
  const int row = blockIdx.x;
  const int tid = threadIdx.x;
  const float* yp = y + (size_t)row * DM;
  const float* rp = resid + (size_t)row * DM;
  float v[4];
  float s = 0.f, sq = 0.f;
  #pragma unroll
  for (int j = 0; j < 4; ++j){
    float t = yp[tid + j * 256] + rp[tid + j * 256];
    v[j] = t; s += t; sq += t * t;
  }
  #pragma unroll
  for (int off = 1; off < 64; off <<= 1){
    s  += __shfl_xor(s, off);
    sq += __shfl_xor(sq, off);
  }
  __shared__ float ls[4], lq[4];
  int wid = tid >> 6;
  if ((tid & 63) == 0){ ls[wid] = s; lq[wid] = sq; }
  __syncthreads();
  s  = ls[0] + ls[1] + ls[2] + ls[3];
  sq = lq[0] + lq[1] + lq[2] + lq[3];
  float mu  = s * (1.f / DM);
  float var = sq * (1.f / DM) - mu * mu;
  float rs  = rsqrtf(var + 1e-5f);
  #pragma unroll
  for (int j = 0; j < 4; ++j){
    int e = tid + j * 256;
    out[(size_t)row * DM + e] = (v[j] - mu) * rs * w[e] + b[e];
  }
}

// ---------------------------------------------------------------------------
extern "C" void kernel_launch(void* const* d_in, const int* in_sizes, int n_in,
                              void* d_out, int out_size, void* d_ws, size_t ws_size,
                              hipStream_t stream)
{
  const float* x_in   = (const float*)d_in[0];
  const float* in_w   = (const float*)d_in[1];
  const float* conv_w = (const float*)d_in[2];
  const float* conv_b = (const float*)d_in[3];
  const float* xp_w   = (const float*)d_in[4];
  const float* dt_w   = (const float*)d_in[5];
  const float* dt_b   = (const float*)d_in[6];
  const float* A_log  = (const float*)d_in[7];
  const float* D_skip = (const float*)d_in[8];
  const float* out_w  = (const float*)d_in[9];
  const float* ln_w   = (const float*)d_in[10];
  const float* ln_b   = (const float*)d_in[11];
  float* out = (float*)d_out;

  float* ws = (float*)d_ws;
  float* xz    = ws;                       // 2*1024*4096 = 8388608
  float* xc    = xz + 8388608;             // 4194304
  float* dbl   = xc + 4194304;             // 196608
  float* delta = dbl + 196608;             // 4194304  (also aliased as scan output y)
  float* xcur  = delta + 4194304;          // 2097152
  float* hend  = xcur + 2097152;           // 1048576  (also aliased as Hinit)
  float* Ss    = hend + 1048576;           // 1048576
  // total ~21.2M floats = ~85 MB

  float* y    = delta;   // pass C writes y in place of delta (tile read into LDS first)
  float* Hin  = hend;    // pass B runs in place
  float* outm = out;     // out_proj scratch = d_out (resid_ln reads-then-writes per row)

  for (int layer = 0; layer < 4; ++layer){
    const float* xl = (layer == 0) ? x_in : xcur;
    float* xnext = (layer == 3) ? out : xcur;
    const float* ALl = A_log + (size_t)layer * DI * 16;
    const float* dtbL = dt_b + (size_t)layer * DI;

    // 1. in_proj: xz[2048,4096] = x[2048,1024] @ W[4096,1024]^T
    gemm_bt<<<dim3(32, 16), 256, 0, stream>>>(
        xl, DM, in_w + (size_t)layer * 4096 * DM, DM, xz, 4096, 4096, DM);
    // 2. conv + silu
    conv_silu<<<16384, 256, 0, stream>>>(
        xz, conv_w + (size_t)layer * DI * 4, conv_b + (size_t)layer * DI, xc);
    // 3. x_proj: dbl[2048,96] = xc[2048,2048] @ Wxp[96,2048]^T
    gemm_bt<<<dim3(1, 16), 256, 0, stream>>>(
        xc, DI, xp_w + (size_t)layer * 96 * DI, DI, dbl, 96, 96, DI);
    // 4. dt_proj: delta_raw[2048,2048] = dbl[:, :64] @ Wdt[2048,64]^T
    gemm_bt<<<dim3(16, 16), 256, 0, stream>>>(
        dbl, 96, dt_w + (size_t)layer * DI * 64, 64, delta, DI, DI, 64);
    // 5-7. selective scan (softplus+bias fused), y = (scan + u*D) * silu(z)
    scan_passA<<<dim3(DI / 256, NCH, NBATCH), 256, 0, stream>>>(
        delta, xc, dbl, dtbL, ALl, hend, Ss);
    scan_passB<<<NBATCH * DI * 16 / 256, 256, 0, stream>>>(hend, Ss, Hin);
    scan_passC<<<dim3(DI / 256, NCH, NBATCH), 256, 0, stream>>>(
        delta, xc, dbl, xz, dtbL, ALl, D_skip + (size_t)layer * DI, Hin, y);
    // 8. out_proj: outm[2048,1024] = y[2048,2048] @ Wout[1024,2048]^T
    gemm_bt<<<dim3(8, 16), 256, 0, stream>>>(
        y, DI, out_w + (size_t)layer * DM * DI, DI, outm, DM, DM, DI);
    // 9. x = LN(outm + x)
    resid_ln<<<NBATCH * LSEQ, 256, 0, stream>>>(
        outm, xl, ln_w + (size_t)layer * DM, ln_b + (size_t)layer * DM, xnext);
  }
}

// Round 8
// 1063.159 us; speedup vs baseline: 1.3898x; 1.3898x over previous
//
#include <hip/hip_runtime.h>
#include <hip/hip_bf16.h>

#define DI 2048
#define DM 1024
#define LSEQ 1024
#define NBATCH 2
#define NCH 64      // number of scan chunks
#define CHUNK 16    // steps per chunk

typedef float f4 __attribute__((ext_vector_type(4)));
typedef short s8v __attribute__((ext_vector_type(8)));
typedef unsigned short u4v __attribute__((ext_vector_type(4)));

__device__ __forceinline__ unsigned short f2bf(float f){
  union { float f; unsigned int u; } v; v.f = f;
  unsigned int u = v.u;
  unsigned int r = u + 0x7fffu + ((u >> 16) & 1u);
  return (unsigned short)(r >> 16);
}

__device__ __forceinline__ float softplus_f(float x){
  return (x > 20.f) ? x : log1pf(__expf(x));
}

// ---------------------------------------------------------------------------
// Weight fp32 -> bf16 pre-convert (same f2bf rounding as in-staging convert,
// so downstream GEMM results are bitwise identical to the fp32-staged path).
// n must be a multiple of 1024; each thread converts 4 consecutive floats.
// ---------------------------------------------------------------------------
__global__ __launch_bounds__(256) void wconv(
    const float* __restrict__ in, unsigned short* __restrict__ o, int n)
{
  int i = blockIdx.x * 256 + threadIdx.x;   // over n/4
  f4 v = *(const f4*)(in + (size_t)i * 4);
  u4v w;
  #pragma unroll
  for (int j = 0; j < 4; ++j) w[j] = f2bf(v[j]);
  *(u4v*)(o + (size_t)i * 4) = w;
}

// ---------------------------------------------------------------------------
// Generic GEMM: C[M,N] = A[M,K] * B[N,K]^T   (row-major fp32 in/out)
// bf16 MFMA 16x16x32, 128x128 tile, BK=32, 256 threads = 4 waves (2x2 of 64x64).
// grid.z enables split-K: block z handles K columns [z*K, (z+1)*K) and writes
// C + z*cz.  For plain GEMM launch grid.z=1, cz=0.
// M % 128 == 0 and K % 32 == 0 required; N guarded.
// ---------------------------------------------------------------------------
__global__ __launch_bounds__(256) void gemm_bt(
    const float* __restrict__ A, int lda,
    const float* __restrict__ B, int ldb,
    float* __restrict__ C, int ldc,
    int N, int K, int cz)
{
  constexpr int BK = 32;
  constexpr int LS = 40;            // padded LDS stride in shorts -> <=2-way conflicts
  __shared__ __align__(16) unsigned short As[128 * LS];
  __shared__ __align__(16) unsigned short Bs[128 * LS];

  const int kb = blockIdx.z * K;
  A += kb; B += kb; C += (size_t)blockIdx.z * cz;

  const int tid  = threadIdx.x;
  const int lane = tid & 63;
  const int wid  = tid >> 6;
  const int wr   = (wid >> 1) * 64;
  const int wc   = (wid & 1) * 64;
  const int m0   = blockIdx.y * 128;
  const int n0   = blockIdx.x * 128;

  const f4 fz = {0.f, 0.f, 0.f, 0.f};
  f4 acc[4][4];
  #pragma unroll
  for (int i = 0; i < 4; ++i)
    #pragma unroll
    for (int j = 0; j < 4; ++j) acc[i][j] = fz;

  f4 ar[4], br[4];

  auto stage_load = [&](int k0){
    #pragma unroll
    for (int i = 0; i < 4; ++i){
      int g = tid + i * 256;
      int r = g >> 3, kk = (g & 7) << 2;
      ar[i] = *(const f4*)(A + (size_t)(m0 + r) * lda + k0 + kk);
      int n = n0 + r;
      br[i] = (n < N) ? *(const f4*)(B + (size_t)n * ldb + k0 + kk) : fz;
    }
  };
  auto stage_write = [&](){
    #pragma unroll
    for (int i = 0; i < 4; ++i){
      int g = tid + i * 256;
      int r = g >> 3, kk = (g & 7) << 2;
      u4v av, bv;
      #pragma unroll
      for (int j = 0; j < 4; ++j){ av[j] = f2bf(ar[i][j]); bv[j] = f2bf(br[i][j]); }
      *(u4v*)(&As[r * LS + kk]) = av;
      *(u4v*)(&Bs[r * LS + kk]) = bv;
    }
  };

  const int nk = K / BK;
  stage_load(0);
  for (int kt = 0; kt < nk; ++kt){
    __syncthreads();
    stage_write();
    __syncthreads();
    if (kt + 1 < nk) stage_load((kt + 1) * BK);

    s8v af[4], bfv[4];
    #pragma unroll
    for (int t = 0; t < 4; ++t){
      af[t]  = *(const s8v*)(&As[(wr + t * 16 + (lane & 15)) * LS + ((lane >> 4) << 3)]);
      bfv[t] = *(const s8v*)(&Bs[(wc + t * 16 + (lane & 15)) * LS + ((lane >> 4) << 3)]);
    }
    #pragma unroll
    for (int mt = 0; mt < 4; ++mt)
      #pragma unroll
      for (int nt = 0; nt < 4; ++nt)
        acc[mt][nt] = __builtin_amdgcn_mfma_f32_16x16x32_bf16(af[mt], bfv[nt], acc[mt][nt], 0, 0, 0);
  }

  #pragma unroll
  for (int mt = 0; mt < 4; ++mt){
    int row = m0 + wr + mt * 16 + ((lane >> 4) << 2);
    #pragma unroll
    for (int nt = 0; nt < 4; ++nt){
      int col = n0 + wc + nt * 16 + (lane & 15);
      if (col < N){
        #pragma unroll
        for (int r = 0; r < 4; ++r)
          C[(size_t)(row + r) * ldc + col] = acc[mt][nt][r];
      }
    }
  }
}

// ---------------------------------------------------------------------------
// Same GEMM but B is PRE-CONVERTED bf16 [N,K] (ushort). A-side, LDS layout,
// fragment reads, MFMA, and C-write are identical to gemm_bt. No split-K.
// M % 128 == 0, N % 128 == 0, K % 32 == 0 required (true for in/out_proj).
// ---------------------------------------------------------------------------
__global__ __launch_bounds__(256) void gemm_btb(
    const float* __restrict__ A, int lda,
    const unsigned short* __restrict__ Bb, int ldb,
    float* __restrict__ C, int ldc,
    int K)
{
  constexpr int BK = 32;
  constexpr int LS = 40;
  __shared__ __align__(16) unsigned short As[128 * LS];
  __shared__ __align__(16) unsigned short Bs[128 * LS];

  const int tid  = threadIdx.x;
  const int lane = tid & 63;
  const int wid  = tid >> 6;
  const int wr   = (wid >> 1) * 64;
  const int wc   = (wid & 1) * 64;
  const int m0   = blockIdx.y * 128;
  const int n0   = blockIdx.x * 128;

  const f4 fz = {0.f, 0.f, 0.f, 0.f};
  f4 acc[4][4];
  #pragma unroll
  for (int i = 0; i < 4; ++i)
    #pragma unroll
    for (int j = 0; j < 4; ++j) acc[i][j] = fz;

  f4 ar[4];      // A fp32 staging regs (4 x 4 floats)
  s8v brb[2];    // B bf16 staging regs (2 x 8 shorts)

  auto stage_load = [&](int k0){
    #pragma unroll
    for (int i = 0; i < 4; ++i){
      int g = tid + i * 256;
      int r = g >> 3, kk = (g & 7) << 2;
      ar[i] = *(const f4*)(A + (size_t)(m0 + r) * lda + k0 + kk);
    }
    #pragma unroll
    for (int i = 0; i < 2; ++i){
      int g = tid + i * 256;          // 0..511
      int r = g >> 2, kk = (g & 3) << 3;   // r: 0..127, kk: 0/8/16/24
      brb[i] = *(const s8v*)(Bb + (size_t)(n0 + r) * ldb + k0 + kk);
    }
  };
  auto stage_write = [&](){
    #pragma unroll
    for (int i = 0; i < 4; ++i){
      int g = tid + i * 256;
      int r = g >> 3, kk = (g & 7) << 2;
      u4v av;
      #pragma unroll
      for (int j = 0; j < 4; ++j) av[j] = f2bf(ar[i][j]);
      *(u4v*)(&As[r * LS + kk]) = av;
    }
    #pragma unroll
    for (int i = 0; i < 2; ++i){
      int g = tid + i * 256;
      int r = g >> 2, kk = (g & 3) << 3;
      *(s8v*)(&Bs[r * LS + kk]) = brb[i];
    }
  };

  const int nk = K / BK;
  stage_load(0);
  for (int kt = 0; kt < nk; ++kt){
    __syncthreads();
    stage_write();
    __syncthreads();
    if (kt + 1 < nk) stage_load((kt + 1) * BK);

    s8v af[4], bfv[4];
    #pragma unroll
    for (int t = 0; t < 4; ++t){
      af[t]  = *(const s8v*)(&As[(wr + t * 16 + (lane & 15)) * LS + ((lane >> 4) << 3)]);
      bfv[t] = *(const s8v*)(&Bs[(wc + t * 16 + (lane & 15)) * LS + ((lane >> 4) << 3)]);
    }
    #pragma unroll
    for (int mt = 0; mt < 4; ++mt)
      #pragma unroll
      for (int nt = 0; nt < 4; ++nt)
        acc[mt][nt] = __builtin_amdgcn_mfma_f32_16x16x32_bf16(af[mt], bfv[nt], acc[mt][nt], 0, 0, 0);
  }

  #pragma unroll
  for (int mt = 0; mt < 4; ++mt){
    int row = m0 + wr + mt * 16 + ((lane >> 4) << 2);
    #pragma unroll
    for (int nt = 0; nt < 4; ++nt){
      int col = n0 + wc + nt * 16 + (lane & 15);
      #pragma unroll
      for (int r = 0; r < 4; ++r)
        C[(size_t)(row + r) * ldc + col] = acc[mt][nt][r];
    }
  }
}

// Reduce split-K partials: dbl[2048*96] = sum over 8 slices.
__global__ __launch_bounds__(256) void xp_reduce(
    const float* __restrict__ p, float* __restrict__ o)
{
  int i = blockIdx.x * 256 + threadIdx.x;   // over 2048*96/4 = 49152 f4's
  const f4* p4 = (const f4*)p;
  f4 s = p4[i];
  #pragma unroll
  for (int z = 1; z < 8; ++z) s += p4[(size_t)z * 49152 + i];
  ((f4*)o)[i] = s;
}

// ---------------------------------------------------------------------------
// Causal depthwise conv1d (k=4) + SiLU. 4 consecutive l per thread.
// xz: [B, L, 2*DI] (xs = cols 0..DI);  xc: [B, L, DI]
// ---------------------------------------------------------------------------
__global__ __launch_bounds__(256) void conv_silu(
    const float* __restrict__ xz, const float* __restrict__ cw,
    const float* __restrict__ cb, float* __restrict__ xc)
{
  int t = blockIdx.x * 256 + threadIdx.x;   // over B*(L/4)*DI
  int d = t & (DI - 1);
  int l4 = (t >> 11) & 255;
  int b = t >> 19;
  int l = l4 * 4;
  f4 w = *(const f4*)(cw + d * 4);
  float bias = cb[d];
  float xv[7];
  #pragma unroll
  for (int k = 0; k < 7; ++k){
    int ls = l - 3 + k;
    xv[k] = (ls >= 0) ? xz[((size_t)(b * LSEQ + ls)) * (2 * DI) + d] : 0.f;
  }
  #pragma unroll
  for (int j = 0; j < 4; ++j){
    float acc = bias + xv[j] * w[0] + xv[j + 1] * w[1] + xv[j + 2] * w[2] + xv[j + 3] * w[3];
    xc[((size_t)(b * LSEQ + l + j)) * DI + d] = acc / (1.f + __expf(-acc));
  }
}

// ---------------------------------------------------------------------------
// Selective scan, chunked-parallel (3 passes), NCH=64 chunks of CHUNK=16.
// delta_raw: [B,L,DI] pre-bias pre-softplus; u: [B,L,DI]; dbl: [B,L,96]
// hend/Ssum/Hinit: [B, NCH, DI, 16]
// ---------------------------------------------------------------------------
__global__ __launch_bounds__(256) void scan_passA(
    const float* __restrict__ delta_raw, const float* __restrict__ u_,
    const float* __restrict__ dbl, const float* __restrict__ dtb_,
    const float* __restrict__ A_log,
    float* __restrict__ hend, float* __restrict__ Ssum)
{
  const int tid = threadIdx.x;
  const int d   = blockIdx.x * 256 + tid;
  const int c   = blockIdx.y;
  const int b   = blockIdx.z;
  const int l0  = c * CHUNK;
  __shared__ float s_bc[CHUNK][32];
  for (int e = tid; e < CHUNK * 32; e += 256){
    int s = e >> 5, j = e & 31;
    s_bc[s][j] = dbl[((size_t)(b * LSEQ + l0 + s)) * 96 + 64 + j];
  }
  float Ar[16];
  #pragma unroll
  for (int n = 0; n < 16; ++n) Ar[n] = -__expf(A_log[(size_t)d * 16 + n]);
  const float dtb = dtb_[d];
  float h[16], S[16];
  #pragma unroll
  for (int n = 0; n < 16; ++n){ h[n] = 0.f; S[n] = 0.f; }
  __syncthreads();
  #pragma unroll
  for (int s = 0; s < CHUNK; ++s){
    size_t idx = ((size_t)(b * LSEQ + l0 + s)) * DI + d;
    float delta = softplus_f(delta_raw[idx] + dtb);
    float du = delta * u_[idx];
    #pragma unroll
    for (int n = 0; n < 16; ++n){
      float x = delta * Ar[n];
      S[n] += x;
      h[n] = h[n] * __expf(x) + du * s_bc[s][n];
    }
  }
  size_t base = (((size_t)b * NCH + c) * DI + d) * 16;
  #pragma unroll
  for (int n = 0; n < 16; ++n){ hend[base + n] = h[n]; Ssum[base + n] = S[n]; }
}

// Inter-chunk recurrence. In-place: Hinit ALIASES hend at launch, so neither
// is __restrict__ (read-before-write per idx must be preserved).
__global__ __launch_bounds__(256) void scan_passB(
    const float* hend, const float* __restrict__ Ssum,
    float* Hinit)
{
  int t = blockIdx.x * 256 + threadIdx.x;   // over B*DI*16
  int n = t & 15;
  int d = (t >> 4) & (DI - 1);
  int b = t >> 15;
  float carry = 0.f;
  for (int c = 0; c < NCH; ++c){
    size_t idx = (((size_t)b * NCH + c) * DI + d) * 16 + n;
    float he = hend[idx];
    float s  = Ssum[idx];
    Hinit[idx] = carry;
    carry = he + __expf(s) * carry;
  }
}

// Final pass: local scan from Hinit, y = C.h + u*D, out = y * silu(z).
// yout aliases delta_raw: the delta tile is preloaded to registers BEFORE any
// store (loads cannot sink past may-alias stores -> safe; do NOT restrict them).
__global__ __launch_bounds__(256) void scan_passC(
    const float* delta_raw, const float* __restrict__ u_,
    const float* __restrict__ dbl, const float* __restrict__ xz,
    const float* __restrict__ dtb_, const float* __restrict__ A_log,
    const float* __restrict__ Dskip_, const float* __restrict__ Hinit,
    float* yout)
{
  const int tid = threadIdx.x;
  const int d   = blockIdx.x * 256 + tid;
  const int c   = blockIdx.y;
  const int b   = blockIdx.z;
  const int l0  = c * CHUNK;
  __shared__ float s_bc[CHUNK][32];
  for (int e = tid; e < CHUNK * 32; e += 256){
    int s = e >> 5, j = e & 31;
    s_bc[s][j] = dbl[((size_t)(b * LSEQ + l0 + s)) * 96 + 64 + j];
  }
  float del[CHUNK];
  #pragma unroll
  for (int s = 0; s < CHUNK; ++s)
    del[s] = delta_raw[((size_t)(b * LSEQ + l0 + s)) * DI + d];

  float Ar[16];
  #pragma unroll
  for (int n = 0; n < 16; ++n) Ar[n] = -__expf(A_log[(size_t)d * 16 + n]);
  const float dtb = dtb_[d];
  const float Dk  = Dskip_[d];
  float h[16];
  size_t hbase = (((size_t)b * NCH + c) * DI + d) * 16;
  #pragma unroll
  for (int n = 0; n < 16; ++n) h[n] = Hinit[hbase + n];
  __syncthreads();
  #pragma unroll
  for (int s = 0; s < CHUNK; ++s){
    size_t idx = ((size_t)(b * LSEQ + l0 + s)) * DI + d;
    float delta = softplus_f(del[s] + dtb);
    float uu = u_[idx];
    float du = delta * uu;
    float y = 0.f;
    #pragma unroll
    for (int n = 0; n < 16; ++n){
      float x = delta * Ar[n];
      h[n] = h[n] * __expf(x) + du * s_bc[s][n];
      y += h[n] * s_bc[s][16 + n];
    }
    y += uu * Dk;
    float z = xz[((size_t)(b * LSEQ + l0 + s)) * (2 * DI) + DI + d];
    yout[idx] = y * (z / (1.f + __expf(-z)));
  }
}

// ---------------------------------------------------------------------------
// residual add + LayerNorm over D=1024. One block per row (b*l).
// y and out MAY ALIAS (layer 3 writes d_out in place) -> no restrict on them.
// ---------------------------------------------------------------------------
__global__ __launch_bounds__(256) void resid_ln(
    const float* y, const float* __restrict__ resid,
    const float* __restrict__ w, const float* __restrict__ b,
    float* out)
{
  const int row = blockIdx.x;
  const int tid = threadIdx.x;
  const float* yp = y + (size_t)row * DM;
  const float* rp = resid + (size_t)row * DM;
  float v[4];
  float s = 0.f, sq = 0.f;
  #pragma unroll
  for (int j = 0; j < 4; ++j){
    float t = yp[tid + j * 256] + rp[tid + j * 256];
    v[j] = t; s += t; sq += t * t;
  }
  #pragma unroll
  for (int off = 1; off < 64; off <<= 1){
    s  += __shfl_xor(s, off);
    sq += __shfl_xor(sq, off);
  }
  __shared__ float ls[4], lq[4];
  int wid = tid >> 6;
  if ((tid & 63) == 0){ ls[wid] = s; lq[wid] = sq; }
  __syncthreads();
  s  = ls[0] + ls[1] + ls[2] + ls[3];
  sq = lq[0] + lq[1] + lq[2] + lq[3];
  float mu  = s * (1.f / DM);
  float var = sq * (1.f / DM) - mu * mu;
  float rs  = rsqrtf(var + 1e-5f);
  #pragma unroll
  for (int j = 0; j < 4; ++j){
    int e = tid + j * 256;
    out[(size_t)row * DM + e] = (v[j] - mu) * rs * w[e] + b[e];
  }
}

// ---------------------------------------------------------------------------
extern "C" void kernel_launch(void* const* d_in, const int* in_sizes, int n_in,
                              void* d_out, int out_size, void* d_ws, size_t ws_size,
                              hipStream_t stream)
{
  const float* x_in   = (const float*)d_in[0];
  const float* in_w   = (const float*)d_in[1];
  const float* conv_w = (const float*)d_in[2];
  const float* conv_b = (const float*)d_in[3];
  const float* xp_w   = (const float*)d_in[4];
  const float* dt_w   = (const float*)d_in[5];
  const float* dt_b   = (const float*)d_in[6];
  const float* A_log  = (const float*)d_in[7];
  const float* D_skip = (const float*)d_in[8];
  const float* out_w  = (const float*)d_in[9];
  const float* ln_w   = (const float*)d_in[10];
  const float* ln_b   = (const float*)d_in[11];
  float* out = (float*)d_out;

  float* ws = (float*)d_ws;
  float* xz    = ws;                       // 8,388,608
  float* xc    = xz + 8388608;             // 4,194,304
  float* dbl   = xc + 4194304;             // 196,608
  float* delta = dbl + 196608;             // 4,194,304  (aliased as scan output y)
  float* xcur  = delta + 4194304;          // 2,097,152
  float* hend  = xcur + 2097152;           // 4,194,304  [B,NCH,DI,16]
  float* Ss    = hend + 4194304;           // 4,194,304
  // total ~27.5M floats = ~110 MB

  float* y    = delta;   // pass C writes y in place of delta (reg-preload first)
  float* Hin  = hend;    // pass B runs in place
  float* xpp  = hend;    // x_proj split-K partials (8*2048*96) -- dead before passA
  float* outm = out;     // out_proj scratch = d_out (resid_ln reads-then-writes per row)

  // bf16 weight buffers alias Ss (4.19M floats = 8.39M shorts):
  //  - in_w_bf16 (4096*1024 = 4.19M shorts) lives in Ss from layer start until
  //    in_proj completes; Ss is only written later by passA.  (timeline-safe)
  //  - out_w_bf16 (1024*2048 = 2.10M shorts) is converted AFTER passB reads Ss
  //    (Ss dead at that point) and consumed by out_proj.
  unsigned short* wbuf = (unsigned short*)Ss;

  for (int layer = 0; layer < 4; ++layer){
    const float* xl = (layer == 0) ? x_in : xcur;
    float* xnext = (layer == 3) ? out : xcur;
    const float* ALl = A_log + (size_t)layer * DI * 16;
    const float* dtbL = dt_b + (size_t)layer * DI;

    // 0a. convert in_proj weights to bf16 (previous layer's Ss is dead)
    wconv<<<4096 * DM / 1024, 256, 0, stream>>>(
        in_w + (size_t)layer * 4096 * DM, wbuf, 4096 * DM);
    // 1. in_proj: xz[2048,4096] = x[2048,1024] @ Wbf16[4096,1024]^T
    gemm_btb<<<dim3(32, 16, 1), 256, 0, stream>>>(
        xl, DM, wbuf, DM, xz, 4096, DM);
    // 2. conv + silu
    conv_silu<<<4096, 256, 0, stream>>>(
        xz, conv_w + (size_t)layer * DI * 4, conv_b + (size_t)layer * DI, xc);
    // 3. x_proj split-K=8: xpp[8][2048,96] = xc @ Wxp^T ; then reduce
    gemm_bt<<<dim3(1, 16, 8), 256, 0, stream>>>(
        xc, DI, xp_w + (size_t)layer * 96 * DI, DI, xpp, 96, 96, 256, 2048 * 96);
    xp_reduce<<<192, 256, 0, stream>>>(xpp, dbl);
    // 4. dt_proj: delta_raw[2048,2048] = dbl[:, :64] @ Wdt[2048,64]^T
    gemm_bt<<<dim3(16, 16, 1), 256, 0, stream>>>(
        dbl, 96, dt_w + (size_t)layer * DI * 64, 64, delta, DI, DI, 64, 0);
    // 5-6. selective scan (softplus+bias fused)
    scan_passA<<<dim3(DI / 256, NCH, NBATCH), 256, 0, stream>>>(
        delta, xc, dbl, dtbL, ALl, hend, Ss);
    scan_passB<<<NBATCH * DI * 16 / 256, 256, 0, stream>>>(hend, Ss, Hin);
    // 6b. convert out_proj weights to bf16 (Ss dead after passB)
    wconv<<<DM * DI / 1024, 256, 0, stream>>>(
        out_w + (size_t)layer * DM * DI, wbuf, DM * DI);
    // 7. scan final pass: y = (scan + u*D) * silu(z)
    scan_passC<<<dim3(DI / 256, NCH, NBATCH), 256, 0, stream>>>(
        delta, xc, dbl, xz, dtbL, ALl, D_skip + (size_t)layer * DI, Hin, y);
    // 8. out_proj: outm[2048,1024] = y[2048,2048] @ Wout_bf16[1024,2048]^T
    gemm_btb<<<dim3(8, 16, 1), 256, 0, stream>>>(
        y, DI, wbuf, DI, outm, DM, DI);
    // 9. x = LN(outm + x)
    resid_ln<<<NBATCH * LSEQ, 256, 0, stream>>>(
        outm, xl, ln_w + (size_t)layer * DM, ln_b + (size_t)layer * DM, xnext);
  }
}